// Round 4
// baseline (79.878 us; speedup 1.0000x reference)
//
#include <hip/hip_runtime.h>
#include <hip/hip_bf16.h>

// out[b, c, m] = weight[idx[b, m], c]   b<256, c<1024, m<64  (fp32, 64 MiB out)
//
// Per-block 64x64 (m x c) LDS transpose, v2:
//  - No idx-staging barrier: each thread loads its 4 row indices directly
//    (16-lane groups share the address -> broadcast), then issues all 4
//    gather float4 loads back-to-back (4-deep MLP) before touching LDS.
//  - Nontemporal output stores (via ext_vector_type float4 — the HIP
//    vector class is rejected by __builtin_nontemporal_store): keep the
//    64 MiB stream from evicting the 4 MiB weight table from L2.
//  - LDS tile [cc][m], PAD=65: both phases verified 2 lanes/bank = free.
//  - Store: 16 KiB fully contiguous per block, float4/lane.

#define BS   256
#define M    64
#define C    1024
#define PAD  65

typedef float v4f __attribute__((ext_vector_type(4)));

__global__ __launch_bounds__(256, 8) void gather_transpose_kernel(
    const int* __restrict__ idx,      // [BS*M] int32
    const float* __restrict__ w,      // [NUM_EMB, C] fp32
    float* __restrict__ out)          // [BS, C, 8, 8] fp32
{
    const int b  = blockIdx.x >> 4;          // 16 channel-tiles per batch
    const int c0 = (blockIdx.x & 15) << 6;   // 64 channels per block

    __shared__ float tile[M * PAD];          // [cc][m], transposed

    const int t  = threadIdx.x;
    const int f  = t & 15;                   // float4 slot within 64-ch slice
    const int mb = t >> 4;                   // base token (row) for this thread

    const int* ib = idx + b * M;

    // ---- index loads (broadcast within 16-lane groups) ----
    int rows[4];
#pragma unroll
    for (int j = 0; j < 4; ++j)
        rows[j] = ib[mb + (j << 4)];

    // ---- gather loads: 4 independent 256B-coalesced row reads in flight ----
    v4f v[4];
#pragma unroll
    for (int j = 0; j < 4; ++j)
        v[j] = *(const v4f*)(w + rows[j] * C + c0 + (f << 2));

    // ---- LDS transpose write (banks (4f+m+k)%32: 2-way, free) ----
#pragma unroll
    for (int j = 0; j < 4; ++j) {
        const int m = mb + (j << 4);
        tile[((f << 2) + 0) * PAD + m] = v[j].x;
        tile[((f << 2) + 1) * PAD + m] = v[j].y;
        tile[((f << 2) + 2) * PAD + m] = v[j].z;
        tile[((f << 2) + 3) * PAD + m] = v[j].w;
    }
    __syncthreads();

    // ---- store phase: 16 KiB contiguous per block, nontemporal ----
    float* obase = out + (((size_t)(b * C + c0)) << 6);
#pragma unroll
    for (int j = 0; j < 4; ++j) {
        const int fo = (j << 8) + t;         // float4 slot 0..1023
        const int cc = fo >> 4;              // channel within tile
        const int m  = (fo & 15) << 2;       // token group of 4
        v4f o;
        o.x = tile[cc * PAD + m + 0];
        o.y = tile[cc * PAD + m + 1];
        o.z = tile[cc * PAD + m + 2];
        o.w = tile[cc * PAD + m + 3];
        __builtin_nontemporal_store(o, (v4f*)(obase + (cc << 6) + m));
    }
}

extern "C" void kernel_launch(void* const* d_in, const int* in_sizes, int n_in,
                              void* d_out, int out_size, void* d_ws, size_t ws_size,
                              hipStream_t stream) {
    const int*   idx = (const int*)d_in[0];    // encoding_indices [256, 64]
    const float* w   = (const float*)d_in[1];  // weight [1024, 1024]
    float*       out = (float*)d_out;          // [256, 1024, 8, 8]

    dim3 grid(BS * (C / 64));  // 4096 blocks
    dim3 block(256);
    gather_transpose_kernel<<<grid, block, 0, stream>>>(idx, w, out);
}